// Round 6
// baseline (72.427 us; speedup 1.0000x reference)
//
#include <hip/hip_runtime.h>
#include <hip/hip_bf16.h>

// MaskedDenseLayerMultiMasks: out[b,m,o] = sum_i x[b,m,i] * kernel[i,o] * masks[m,i,o]
// bf16 MFMA GEMM, fused convert + mask-multiply during reg staging.
// Round 6: (1) compiler __bf16 casts (v_cvt_pk_bf16_f32) instead of hand RNE
// bit-twiddle -- ~4x less convert VALU (m240); (2) 256-thr / 128x64 tiles ->
// 4 blocks/CU = 4 independent barrier domains (latency-bound => more TLP);
// (3) 2-deep B register pipeline now fits VGPR budget; raw s_barrier +
// lgkmcnt(0) only (no vmcnt drain); (4) B LDS stride 34 + granule XOR.

#define BATCH 512
#define NMASK 16
#define IN_D  1024
#define OUT_D 1024

#define BM 128
#define BN 64
#define BK 32
#define NT (IN_D / BK)   // 32
#define AKP 40           // A LDS k-stride (80B rows)
#define BKP 34           // B LDS k-stride (68B rows) + granule XOR
#define THREADS 256

using bf16x8 = __attribute__((ext_vector_type(8))) __bf16;
using bf16x4 = __attribute__((ext_vector_type(4))) __bf16;
using f32x4  = __attribute__((ext_vector_type(4))) float;
using f32x2  = __attribute__((ext_vector_type(2))) float;

struct BRegs { f32x2 kv[4]; f32x2 mv[4]; };

__device__ __forceinline__ int physg(int g, int o) { return g ^ (o & 7); }

__global__ void __launch_bounds__(THREADS, 4)
mdl_mfma_kernel(const float* __restrict__ X,   // (B, M, I)
                const float* __restrict__ Kn,  // (I, O)
                const float* __restrict__ Mk,  // (M, I, O)
                float* __restrict__ Out)       // (B, M, O)
{
    __shared__ __align__(16) unsigned short As[2][BM * AKP];  // 20.0 KiB
    __shared__ __align__(16) unsigned short Bs[2][BN * BKP];  // 8.5 KiB

    const int t = threadIdx.x;
    const int l = t & 63;
    const int w = t >> 6;          // wave 0..3

    // XCD-aware bijective swizzle: 1024 wgs, 8 XCDs, 128 contiguous wgs/XCD.
    // wg = m*64 + ob*4 + bb : bb innermost so the 4 blocks sharing a B-panel
    // are co-resident; each XCD owns 2 masks.
    const int raw = blockIdx.x;
    const int wg  = (raw & 7) * 128 + (raw >> 3);
    const int m   = wg >> 6;          // 0..15
    const int ob  = (wg >> 2) & 15;   // 0..15
    const int bb  = wg & 3;           // 0..3

    // wave -> 64x32 sub-tile of the 128x64 block tile
    const int wr = w >> 1;            // 0..1
    const int wc = w & 1;             // 0..1

    f32x4 acc[4][2];
#pragma unroll
    for (int mi = 0; mi < 4; ++mi)
#pragma unroll
        for (int ni = 0; ni < 2; ++ni)
            acc[mi][ni] = (f32x4){0.f, 0.f, 0.f, 0.f};

    // A staging: 2 threads per row: row = t>>1 (0..127), k-half = (t&1)*16
    const int a_row = t >> 1;
    const int a_kh  = (t & 1) * 16;
    // B staging: 4i x 2o patch: o = 2*(t&31)+c, i = (t>>5)*4+r
    const int o_l = (t & 31) * 2;
    const int ig  = t >> 5;           // 0..7
    const int i_l = ig * 4;

    const float* Xa  = X + ((size_t)(bb * BM + a_row) * NMASK + m) * IN_D + a_kh;
    const float* Knb = Kn + (size_t)i_l * OUT_D + ob * BN + o_l;
    const float* Mkb = Mk + ((size_t)m * IN_D + i_l) * OUT_D + ob * BN + o_l;

    f32x4 av[4];         // A pipeline (1-deep): 16 floats
    BRegs b0, b1;        // B pipeline (2-deep, named copies; rule #20)

    auto LOADA = [&](int kt) {
#pragma unroll
        for (int j = 0; j < 4; ++j)
            av[j] = *(const f32x4*)(Xa + kt + j * 4);
    };
    auto LOADB = [&](BRegs& bg, int kt) {
#pragma unroll
        for (int r = 0; r < 4; ++r) {
            bg.kv[r] = *(const f32x2*)(Knb + (size_t)(kt + r) * OUT_D);
            bg.mv[r] = *(const f32x2*)(Mkb + (size_t)(kt + r) * OUT_D);
        }
    };
    auto STORE = [&](int buf, BRegs& bg) {
        // B first: loads are 1+ iters old -> counted vmcnt, new loads stay in flight
#pragma unroll
        for (int c = 0; c < 2; ++c) {
            const int o = o_l + c;
            bf16x4 v;
#pragma unroll
            for (int r = 0; r < 4; ++r)
                v[r] = (__bf16)(bg.kv[r][c] * bg.mv[r][c]);   // cvt_pk path
            *(bf16x4*)(&Bs[buf][o * BKP + physg(ig, o) * 4]) = v;
        }
        // A second (L2-hot, this-iter loads; wait covered by MFMA below it)
        bf16x8 va0, va1;
#pragma unroll
        for (int j = 0; j < 4; ++j) {
            va0[j]     = (__bf16)av[0][j];  va0[4 + j] = (__bf16)av[1][j];
            va1[j]     = (__bf16)av[2][j];  va1[4 + j] = (__bf16)av[3][j];
        }
        *(bf16x8*)(&As[buf][a_row * AKP + a_kh])     = va0;
        *(bf16x8*)(&As[buf][a_row * AKP + a_kh + 8]) = va1;
    };
    auto MFMA_PHASE = [&](int buf) {
        const int kg = (l >> 4) * 8;          // k-offset of this lane's frag
        const int Gb = (l >> 4) * 2;          // granule index (4 elems/granule)
        bf16x8 bfv[2];
#pragma unroll
        for (int ni = 0; ni < 2; ++ni) {
            const int n = wc * 32 + ni * 16 + (l & 15);
            bf16x4 lo = *(const bf16x4*)(&Bs[buf][n * BKP + physg(Gb, n) * 4]);
            bf16x4 hi = *(const bf16x4*)(&Bs[buf][n * BKP + physg(Gb + 1, n) * 4]);
            bf16x8 f;
            f[0] = lo[0]; f[1] = lo[1]; f[2] = lo[2]; f[3] = lo[3];
            f[4] = hi[0]; f[5] = hi[1]; f[6] = hi[2]; f[7] = hi[3];
            bfv[ni] = f;
        }
#pragma unroll
        for (int mi = 0; mi < 4; ++mi) {
            const int r = wr * 64 + mi * 16 + (l & 15);
            bf16x8 af = *(const bf16x8*)(&As[buf][r * AKP + kg]);
#pragma unroll
            for (int ni = 0; ni < 2; ++ni)
                acc[mi][ni] = __builtin_amdgcn_mfma_f32_16x16x32_bf16(
                    af, bfv[ni], acc[mi][ni], 0, 0, 0);
        }
    };
    auto BARRIER = [&]() {
        asm volatile("s_waitcnt lgkmcnt(0)" ::: "memory");  // ds_writes visible
        __builtin_amdgcn_sched_barrier(0);
        __builtin_amdgcn_s_barrier();                       // NO vmcnt drain
        __builtin_amdgcn_sched_barrier(0);
    };

    // ---- prologue: tile0 -> buf0; tile1 B-loads in flight ----
    LOADA(0);
    LOADB(b0, 0);
    STORE(0, b0);
    LOADB(b1, BK);
    BARRIER();

    // ---- main loop, 2x unrolled for static b0/b1 roles; 1 barrier/tile ----
    for (int tt = 0; tt < NT; tt += 2) {
        // even: compute buf0 (tile tt); store tile tt+1 -> buf1 from b1
        if (tt + 1 < NT) LOADA((tt + 1) * BK);
        if (tt + 2 < NT) LOADB(b0, (tt + 2) * BK);
        __builtin_amdgcn_sched_barrier(0);
        MFMA_PHASE(0);
        if (tt + 1 < NT) STORE(1, b1);
        BARRIER();
        // odd: compute buf1 (tile tt+1); store tile tt+2 -> buf0 from b0
        if (tt + 2 < NT) LOADA((tt + 2) * BK);
        if (tt + 3 < NT) LOADB(b1, (tt + 3) * BK);
        __builtin_amdgcn_sched_barrier(0);
        MFMA_PHASE(1);
        if (tt + 2 < NT) STORE(0, b0);
        BARRIER();
    }

    // ---- epilogue: C/D layout col = l&15, row = (l>>4)*4 + reg ----
    const int r0 = bb * BM + wr * 64 + (l >> 4) * 4;
    const int c0 = ob * BN + wc * 32 + (l & 15);
#pragma unroll
    for (int mi = 0; mi < 4; ++mi) {
#pragma unroll
        for (int j = 0; j < 4; ++j) {
            const size_t row = (size_t)(r0 + mi * 16 + j);
            float* op = Out + (row * NMASK + m) * OUT_D + c0;
#pragma unroll
            for (int ni = 0; ni < 2; ++ni)
                op[ni * 16] = acc[mi][ni][j];
        }
    }
}

extern "C" void kernel_launch(void* const* d_in, const int* in_sizes, int n_in,
                              void* d_out, int out_size, void* d_ws, size_t ws_size,
                              hipStream_t stream) {
    (void)in_sizes; (void)n_in; (void)d_ws; (void)ws_size; (void)out_size;
    const float* X  = (const float*)d_in[0];
    const float* Kn = (const float*)d_in[1];
    const float* Mk = (const float*)d_in[2];
    float* Out = (float*)d_out;

    const int nblocks = (BATCH / BM) * (OUT_D / BN) * NMASK;  // 4*16*16 = 1024
    mdl_mfma_kernel<<<nblocks, THREADS, 0, stream>>>(X, Kn, Mk, Out);
}

// Round 7
// 56.683 us; speedup vs baseline: 1.2778x; 1.2778x over previous
//
#include <hip/hip_runtime.h>
#include <hip/hip_bf16.h>

// MaskedDenseLayerMultiMasks: out[b,m,o] = sum_i x[b,m,i] * kernel[i,o] * masks[m,i,o]
// bf16 MFMA GEMM, fused convert + mask-multiply during reg staging.
// Round 7: GEOMETRY attack (scheduling grafts r4-r6 were null):
//  - BM=256 x BN=128 tiles: W-panel redundancy 4->2, L2 traffic ~800->~400 MB
//  - 8 waves x (64x64) wave tiles + mfma_f32_32x32x16_bf16: halves LDS frag
//    reads (8 b128/wave/iter) and halves MFMA-pipe cycles vs 16x16x32
//  - bijective 16B-pair XOR swizzle (p ^ ((row>>3)&3)) on stride-40 rows:
//    frag reads conflict-free, staging writes <=4-way
//  - r4 loop order kept: LOAD(t+1); MFMA(cur); STORE(->cur^1); raw s_barrier
//    + lgkmcnt(0) only (no vmcnt drain)

#define BATCH 512
#define NMASK 16
#define IN_D  1024
#define OUT_D 1024

#define BM 256
#define BN 128
#define BK 32
#define NT (IN_D / BK)   // 32
#define AKP 40           // LDS k-stride (elements); 80B rows cover all 8 phases
#define THREADS 512

using bf16x8 = __attribute__((ext_vector_type(8))) __bf16;
using bf16x4 = __attribute__((ext_vector_type(4))) __bf16;
using f32x16 = __attribute__((ext_vector_type(16))) float;
using f32x4  = __attribute__((ext_vector_type(4))) float;
using f32x2  = __attribute__((ext_vector_type(2))) float;

__global__ void __launch_bounds__(THREADS, 4)
mdl_mfma_kernel(const float* __restrict__ X,   // (B, M, I)
                const float* __restrict__ Kn,  // (I, O)
                const float* __restrict__ Mk,  // (M, I, O)
                float* __restrict__ Out)       // (B, M, O)
{
    __shared__ __align__(16) unsigned short As[2][BM * AKP];  // 40 KiB total
    __shared__ __align__(16) unsigned short Bs[2][BN * AKP];  // 20 KiB total

    const int t = threadIdx.x;
    const int l = t & 63;
    const int w = t >> 6;          // wave 0..7

    // XCD swizzle: 256 wgs, 8 XCDs, 32 contiguous wgs/XCD (= 2 masks each).
    // wg = m*16 + ob*2 + bb: bb innermost (B-panel sharers adjacent).
    const int raw = blockIdx.x;
    const int wg  = (raw & 7) * 32 + (raw >> 3);
    const int m   = wg >> 4;          // 0..15
    const int ob  = (wg >> 1) & 7;    // 0..7
    const int bb  = wg & 1;           // 0..1

    // wave -> 64x64 sub-tile: 4 row-groups x 2 col-groups
    const int wrow = (w >> 1) * 64;   // 0,64,128,192
    const int wcol = (w & 1) * 64;    // 0,64

    f32x16 acc[2][2];
#pragma unroll
    for (int ti = 0; ti < 2; ++ti)
#pragma unroll
        for (int tj = 0; tj < 2; ++tj)
#pragma unroll
            for (int e = 0; e < 16; ++e)
                acc[ti][tj][e] = 0.f;

    // A staging: 2 threads/row: row = t>>1 (0..255), k-half = (t&1)*16
    const int a_row = t >> 1;
    const int a_kh  = (t & 1) * 16;
    const int a_x   = (a_row >> 3) & 3;          // A swizzle bits for this row
    const int a_p0  = (t & 1) * 2;               // logical 16B-pair of va0
    // B staging: o-pair = 2*(t&63), k-quad = w*4
    const int o2  = (t & 63) * 2;
    const int kq  = w * 4;

    const float* Xa  = X + ((size_t)(bb * BM + a_row) * NMASK + m) * IN_D + a_kh;
    const float* Knb = Kn + (size_t)kq * OUT_D + ob * BN + o2;
    const float* Mkb = Mk + ((size_t)m * IN_D + kq) * OUT_D + ob * BN + o2;

    f32x4 av[4];               // A staging: 16 floats
    f32x2 kv[4], mv[4];        // B staging: 16 floats

    auto LOAD = [&](int kt) {
#pragma unroll
        for (int j = 0; j < 4; ++j)
            av[j] = *(const f32x4*)(Xa + kt + j * 4);
#pragma unroll
        for (int r = 0; r < 4; ++r) {
            kv[r] = *(const f32x2*)(Knb + (size_t)(kt + r) * OUT_D);
            mv[r] = *(const f32x2*)(Mkb + (size_t)(kt + r) * OUT_D);
        }
    };

    auto STORE = [&](int buf) {
        // B first (older pending loads drain first in counted vmcnt order)
#pragma unroll
        for (int c = 0; c < 2; ++c) {
            const int o  = o2 + c;
            const int xb = (o >> 3) & 3;
            bf16x4 v;
#pragma unroll
            for (int r = 0; r < 4; ++r)
                v[r] = (__bf16)(kv[r][c] * mv[r][c]);
            *(bf16x4*)(&Bs[buf][o * AKP + (((w >> 1) ^ xb) * 8) + (w & 1) * 4]) = v;
        }
        bf16x8 va0, va1;
#pragma unroll
        for (int j = 0; j < 4; ++j) {
            va0[j] = (__bf16)av[0][j];  va0[4 + j] = (__bf16)av[1][j];
            va1[j] = (__bf16)av[2][j];  va1[4 + j] = (__bf16)av[3][j];
        }
        *(bf16x8*)(&As[buf][a_row * AKP + ((a_p0 ^ a_x) * 8)])       = va0;
        *(bf16x8*)(&As[buf][a_row * AKP + (((a_p0 + 1) ^ a_x) * 8)]) = va1;
    };

    auto MFMA_PHASE = [&](int buf) {
#pragma unroll
        for (int s = 0; s < 2; ++s) {
            const int p = s * 2 + (l >> 5);     // logical 16B-pair (k-window)
            bf16x8 af[2], bfv[2];
#pragma unroll
            for (int ti = 0; ti < 2; ++ti) {
                const int r  = wrow + ti * 32 + (l & 31);
                const int xa = (r >> 3) & 3;
                af[ti] = *(const bf16x8*)(&As[buf][r * AKP + ((p ^ xa) * 8)]);
            }
#pragma unroll
            for (int tj = 0; tj < 2; ++tj) {
                const int o  = wcol + tj * 32 + (l & 31);
                const int xb = (o >> 3) & 3;
                bfv[tj] = *(const bf16x8*)(&Bs[buf][o * AKP + ((p ^ xb) * 8)]);
            }
#pragma unroll
            for (int ti = 0; ti < 2; ++ti)
#pragma unroll
                for (int tj = 0; tj < 2; ++tj)
                    acc[ti][tj] = __builtin_amdgcn_mfma_f32_32x32x16_bf16(
                        af[ti], bfv[tj], acc[ti][tj], 0, 0, 0);
        }
    };

    auto BARRIER = [&]() {
        asm volatile("s_waitcnt lgkmcnt(0)" ::: "memory");
        __builtin_amdgcn_sched_barrier(0);
        __builtin_amdgcn_s_barrier();
        __builtin_amdgcn_sched_barrier(0);
    };

    // ---- prologue ----
    LOAD(0);
    STORE(0);
    BARRIER();

    // ---- main loop: 1 barrier per K-tile ----
    for (int tt = 0; tt < NT; ++tt) {
        const int cur = tt & 1;
        if (tt + 1 < NT) {
            LOAD((tt + 1) * BK);
            __builtin_amdgcn_sched_barrier(0);
        }
        MFMA_PHASE(cur);
        if (tt + 1 < NT) STORE(cur ^ 1);
        BARRIER();
    }

    // ---- epilogue: C/D 32x32 layout: col = l&31, row = (reg&3)+8*(reg>>2)+4*(l>>5) ----
    const int r0 = bb * BM + wrow + 4 * (l >> 5);
    const int c0 = ob * BN + wcol + (l & 31);
#pragma unroll
    for (int ti = 0; ti < 2; ++ti) {
#pragma unroll
        for (int tj = 0; tj < 2; ++tj) {
#pragma unroll
            for (int g = 0; g < 4; ++g) {
#pragma unroll
                for (int q = 0; q < 4; ++q) {
                    const int row = r0 + ti * 32 + g * 8 + q;
                    const int col = c0 + tj * 32;
                    Out[((size_t)row * NMASK + m) * OUT_D + col] = acc[ti][tj][g * 4 + q];
                }
            }
        }
    }
}

extern "C" void kernel_launch(void* const* d_in, const int* in_sizes, int n_in,
                              void* d_out, int out_size, void* d_ws, size_t ws_size,
                              hipStream_t stream) {
    (void)in_sizes; (void)n_in; (void)d_ws; (void)ws_size; (void)out_size;
    const float* X  = (const float*)d_in[0];
    const float* Kn = (const float*)d_in[1];
    const float* Mk = (const float*)d_in[2];
    float* Out = (float*)d_out;

    const int nblocks = (BATCH / BM) * (OUT_D / BN) * NMASK;  // 2*8*16 = 256
    mdl_mfma_kernel<<<nblocks, THREADS, 0, stream>>>(X, Kn, Mk, Out);
}

// Round 8
// 52.186 us; speedup vs baseline: 1.3879x; 1.0862x over previous
//
#include <hip/hip_runtime.h>
#include <hip/hip_bf16.h>

// MaskedDenseLayerMultiMasks: out[b,m,o] = sum_i x[b,m,i] * kernel[i,o] * masks[m,i,o]
// Round 8: masks (the only HBM-latency stream) are prefetched 1 iter ahead via
// global_load_lds DMA into a raw-f32 LDS tile (no VGPRs held -> the register
// allocator cannot collapse the pipeline, which killed r4-r6). Staging reads
// mask f32 from LDS, multiplies with L2-hot Kn regs, converts, writes r4's
// proven bf16 As/Bs layouts. m97 structure: STAGE-next -> compute -> vmcnt(0)
// + barrier.

#define BATCH 512
#define NMASK 16
#define IN_D  1024
#define OUT_D 1024

#define BM 128
#define BN 128
#define BK 32
#define NT (IN_D / BK)   // 32
#define AKP 40           // A LDS k-stride (80B rows)
#define BKP 34           // B LDS k-stride (68B rows)
#define THREADS 512

using bf16x8 = __attribute__((ext_vector_type(8))) __bf16;
using bf16x4 = __attribute__((ext_vector_type(4))) __bf16;
using f32x4  = __attribute__((ext_vector_type(4))) float;
using f32x2  = __attribute__((ext_vector_type(2))) float;

typedef const __attribute__((address_space(1))) void gvoid_t;
typedef __attribute__((address_space(3))) void lvoid_t;

// async 16B/lane global->LDS DMA; LDS dest is wave-uniform base + lane*16
__device__ __forceinline__ void dma16(const void* g, const void* l) {
    __builtin_amdgcn_global_load_lds((gvoid_t*)(uintptr_t)g,
                                     (lvoid_t*)(uintptr_t)l, 16, 0, 0);
}

__global__ void __launch_bounds__(THREADS, 4)
mdl_mfma_kernel(const float* __restrict__ X,   // (B, M, I)
                const float* __restrict__ Kn,  // (I, O)
                const float* __restrict__ Mk,  // (M, I, O)
                float* __restrict__ Out)       // (B, M, O)
{
    __shared__ __align__(16) float          Mf[2][BK * BN];   // raw f32 masks, 32 KiB
    __shared__ __align__(16) unsigned short As[2][BM * AKP];  // 20 KiB
    __shared__ __align__(16) unsigned short Bs[2][BN * BKP];  // 17 KiB

    const int t = threadIdx.x;
    const int l = t & 63;
    const int w = t >> 6;          // wave 0..7

    // XCD-aware bijective swizzle: 512 wgs, 8 XCDs, 64 contiguous wgs/XCD.
    const int raw = blockIdx.x;
    const int wg  = (raw & 7) * 64 + (raw >> 3);
    const int m   = wg >> 5;          // 0..15
    const int ob  = (wg >> 2) & 7;    // 0..7
    const int bb  = wg & 3;           // 0..3

    // wave -> 64x32 sub-tile (r4's proven map)
    const int wr = w >> 2;            // 0..1
    const int wc = w & 3;             // 0..3

    f32x4 acc[4][2];
#pragma unroll
    for (int mi = 0; mi < 4; ++mi)
#pragma unroll
        for (int ni = 0; ni < 2; ++ni)
            acc[mi][ni] = (f32x4){0.f, 0.f, 0.f, 0.f};

    // A staging: row = t>>2 (0..127), k-half = (t&3)*8
    const int a_row = t >> 2;
    const int a_kh  = (t & 3) * 8;
    // B staging: thread owns [4k][2o]: o2 = 2*(t&63), k4 = w*4
    const int o2 = (t & 63) * 2;
    const int k4 = w * 4;

    const int obase = ob * BN;
    const float* Xa  = X + ((size_t)(bb * BM + a_row) * NMASK + m) * IN_D + a_kh;
    const float* Knb = Kn + obase + o2;
    const float* Mkm = Mk + (size_t)m * IN_D * OUT_D;

    // DMA map: issue j in {0,1}; lane l covers mask row k = j*16 + w*2 + (l>>5),
    // o-quad (l&31)*4; LDS byte base (uniform/wave) = j*8192 + w*1024.
    auto DMA = [&](int tile, int buf) {
        const int kt = tile * BK;
#pragma unroll
        for (int j = 0; j < 2; ++j) {
            const int k = j * 16 + w * 2 + (l >> 5);
            const float* gsrc = Mkm + (size_t)(kt + k) * OUT_D + obase + (l & 31) * 4;
            const float* ldst = &Mf[buf][j * 2048 + w * 256];
            dma16(gsrc, ldst);
        }
    };

    auto MFMA_PHASE = [&](int buf) {
        const int kg = (l >> 4) * 8;
        bf16x8 bfv[2];
#pragma unroll
        for (int ni = 0; ni < 2; ++ni) {
            const int n = wc * 32 + ni * 16 + (l & 15);
            bf16x4 lo = *(const bf16x4*)(&Bs[buf][n * BKP + kg]);
            bf16x4 hi = *(const bf16x4*)(&Bs[buf][n * BKP + kg + 4]);
            bf16x8 f;
            f[0] = lo[0]; f[1] = lo[1]; f[2] = lo[2]; f[3] = lo[3];
            f[4] = hi[0]; f[5] = hi[1]; f[6] = hi[2]; f[7] = hi[3];
            bfv[ni] = f;
        }
#pragma unroll
        for (int mi = 0; mi < 4; ++mi) {
            const int r = wr * 64 + mi * 16 + (l & 15);
            bf16x8 af = *(const bf16x8*)(&As[buf][r * AKP + kg]);
#pragma unroll
            for (int ni = 0; ni < 2; ++ni)
                acc[mi][ni] = __builtin_amdgcn_mfma_f32_16x16x32_bf16(
                    af, bfv[ni], acc[mi][ni], 0, 0, 0);
        }
    };

    // ---- prologue: DMA mask tile 0, wait, barrier ----
    DMA(0, 0);
    asm volatile("s_waitcnt vmcnt(0)" ::: "memory");
    __builtin_amdgcn_s_barrier();
    __builtin_amdgcn_sched_barrier(0);

    for (int tt = 0; tt < NT; ++tt) {
        const int cur = tt & 1;
        const int kt  = tt * BK;

        // a1: X / Kn loads for THIS tile (L2-hot; issued before DMA so their
        //     dataflow wait is a counted vmcnt leaving the DMA in flight)
        f32x4 xv0 = *(const f32x4*)(Xa + kt);
        f32x4 xv1 = *(const f32x4*)(Xa + kt + 4);
        f32x2 kv[4];
#pragma unroll
        for (int r = 0; r < 4; ++r)
            kv[r] = *(const f32x2*)(Knb + (size_t)(kt + k4 + r) * OUT_D);
        __builtin_amdgcn_sched_barrier(0);

        // a2: DMA NEXT mask tile (consumed next iter)
        if (tt + 1 < NT) DMA(tt + 1, cur ^ 1);
        __builtin_amdgcn_sched_barrier(0);

        // b: staging tile t -> As/Bs[cur]
        {
            // B: mask f32 from LDS (DMA'd last iter) * Kn, transpose, b64 writes
            f32x2 mvv[4];
#pragma unroll
            for (int r = 0; r < 4; ++r)
                mvv[r] = *(const f32x2*)(&Mf[cur][(k4 + r) * BN + o2]);
#pragma unroll
            for (int c = 0; c < 2; ++c) {
                bf16x4 v;
#pragma unroll
                for (int r = 0; r < 4; ++r)
                    v[r] = (__bf16)(kv[r][c] * mvv[r][c]);
                *(bf16x4*)(&Bs[cur][(o2 + c) * BKP + k4]) = v;
            }
            // A: convert, one b128 write
            bf16x8 va;
#pragma unroll
            for (int j = 0; j < 4; ++j) {
                va[j]     = (__bf16)xv0[j];
                va[4 + j] = (__bf16)xv1[j];
            }
            *(bf16x8*)(&As[cur][a_row * AKP + a_kh]) = va;
        }

        // c: staging visible to all waves
        asm volatile("s_waitcnt lgkmcnt(0)" ::: "memory");
        __builtin_amdgcn_sched_barrier(0);
        __builtin_amdgcn_s_barrier();
        __builtin_amdgcn_sched_barrier(0);

        // d: compute
        MFMA_PHASE(cur);

        // e: all waves' DMAs for t+1 landed before anyone reads Mf[cur^1]
        asm volatile("s_waitcnt vmcnt(0)" ::: "memory");
        __builtin_amdgcn_sched_barrier(0);
        __builtin_amdgcn_s_barrier();
        __builtin_amdgcn_sched_barrier(0);
    }

    // ---- epilogue: C/D layout col = l&15, row = (l>>4)*4 + reg ----
    const int r0 = bb * BM + wr * 64 + (l >> 4) * 4;
    const int c0 = ob * BN + wc * 32 + (l & 15);
#pragma unroll
    for (int mi = 0; mi < 4; ++mi) {
#pragma unroll
        for (int j = 0; j < 4; ++j) {
            const size_t row = (size_t)(r0 + mi * 16 + j);
            float* op = Out + (row * NMASK + m) * OUT_D + c0;
#pragma unroll
            for (int ni = 0; ni < 2; ++ni)
                op[ni * 16] = acc[mi][ni][j];
        }
    }
}

extern "C" void kernel_launch(void* const* d_in, const int* in_sizes, int n_in,
                              void* d_out, int out_size, void* d_ws, size_t ws_size,
                              hipStream_t stream) {
    (void)in_sizes; (void)n_in; (void)d_ws; (void)ws_size; (void)out_size;
    const float* X  = (const float*)d_in[0];
    const float* Kn = (const float*)d_in[1];
    const float* Mk = (const float*)d_in[2];
    float* Out = (float*)d_out;

    const int nblocks = (BATCH / BM) * (OUT_D / BN) * NMASK;  // 512
    mdl_mfma_kernel<<<nblocks, THREADS, 0, stream>>>(X, Kn, Mk, Out);
}